// Round 4
// baseline (411.390 us; speedup 1.0000x reference)
//
#include <hip/hip_runtime.h>

// ROI adaptive average pooling — LDS-gather with paired ds_read2_b32.
// B=8, C=1024, HW=14, N=512, FS=14, SCALE=1/16.
//
// R3 post-mortem: kernel ~81us vs 65us write floor; LDS pipe (16 ds_read_b32
// per quad ~93cyc/wave) was nearly as loaded as the HBM-store pipe (~102cyc).
// Fix: v01 always lives at O00+4B when its weight mw=1 (and is masked by
// mw=0 otherwise), same for v11 at O10+4B. Loading adjacent dwords from one
// base lets the compiler merge into ds_read2_b32 -> 8 DS ops/quad (~48cyc),
// firmly below the store cost. Drops the o01/o11/mwh tables. s_plane gets a
// 4-float zero pad: the unconditional +4 read can overshoot the last plane
// by one element (garbage NaN * 0.0 would poison the fma otherwise).
//
// Block = 1 ROI x 32 channels: planes (25,104 B) + geometry (3,920 B) -> 5
// blocks/CU, 20 waves/CU. Floor: HBM write 411 MB ~= 65 us.

#define FS_      14
#define PER_CH   196               // 14*14
#define C_       1024
#define CPB      32                // channels per block
#define QPC      49                // float4-quads per channel (196/4)
#define NSTAGE4  (CPB * PER_CH / 4)  // 1568 float4 to stage
#define ACT      245               // active compute threads = 5*49

__global__ __launch_bounds__(256) void roi_pool_kernel(
    const float* __restrict__ tensor,
    const float* __restrict__ roi,
    float* __restrict__ out)
{
    __shared__ float s_plane[CPB * PER_CH + 4];                   // +4 pad
    __shared__ alignas(16) int   s_o00[PER_CH], s_o10[PER_CH];    // byte offsets
    __shared__ alignas(16) float s_mw[PER_CH], s_mh[PER_CH], s_inv[PER_CH];

    const unsigned bx = blockIdx.x;
    const unsigned n  = bx >> 5;            // ROI index
    const unsigned c0 = (bx & 31u) * CPB;   // first channel of this block

    // ROI row [batch_idx, x1, y1, x2, y2] in 224-px coords (uniform -> scalar).
    const float* r = roi + n * 5;
    const int fm = (int)r[0];
    const int x1 = max((int)floorf(r[1] * 0.0625f), 0);
    const int y1 = max((int)floorf(r[2] * 0.0625f), 0);
    const int x2 = min((int)ceilf(r[3] * 0.0625f), FS_);
    const int y2 = min((int)ceilf(r[4] * 0.0625f), FS_);
    const unsigned Lh = (unsigned)(x2 - x1);   // 1..14 guaranteed
    const unsigned Lw = (unsigned)(y2 - y1);

    const unsigned tid = threadIdx.x;

    // ---- Phase 1a: geometry tables (196 positions) + zero the pad.
    if (tid < PER_CH) {
        const unsigned p = tid;
        const unsigned i = p / 14u;
        const unsigned j = p - i * 14u;
        const unsigned h0 = (i * Lh) / 14u;
        const unsigned h1 = ((i + 1u) * Lh + 13u) / 14u;
        const unsigned w0 = (j * Lw) / 14u;
        const unsigned w1 = ((j + 1u) * Lw + 13u) / 14u;
        const int dh = (int)(h1 - h0) - 1;     // 0 or 1
        const int dw = (int)(w1 - w0) - 1;     // 0 or 1
        const int a00 = (x1 + (int)h0) * FS_ + (y1 + (int)w0);
        s_o00[p] = a00 * 4;
        s_o10[p] = (a00 + FS_ * dh) * 4;
        s_mw[p]  = (float)dw;
        s_mh[p]  = (float)dh;
        const int cnt = (dh + 1) * (dw + 1);   // 1, 2, or 4
        s_inv[p] = (cnt == 1) ? 1.0f : ((cnt == 2) ? 0.5f : 0.25f);
    } else if (tid >= 252u) {
        s_plane[CPB * PER_CH + (tid - 252u)] = 0.0f;   // zero the pad
    }

    // ---- Phase 1b: stage the 32 contiguous input planes (coalesced float4).
    const float4* __restrict__ src4 =
        (const float4*)(tensor + ((size_t)fm * C_ + c0) * PER_CH);
    float4* __restrict__ dst4 = (float4*)s_plane;
#pragma unroll
    for (unsigned k = 0; k < 7; ++k) {
        unsigned fi = k * 256u + tid;
        if (fi < NSTAGE4) dst4[fi] = src4[fi];
    }

    __syncthreads();

    // ---- Phase 2: each active thread owns quad q of every 5th channel.
    if (tid < ACT) {
        const unsigned tc = tid / QPC;         // 0..4
        const unsigned q  = tid - tc * QPC;    // fixed across iterations

        const int4   O00 = ((const int4*)s_o00)[q];
        const int4   O10 = ((const int4*)s_o10)[q];
        const float4 MW  = ((const float4*)s_mw)[q];
        const float4 MH  = ((const float4*)s_mh)[q];
        const float4 INV = ((const float4*)s_inv)[q];

        float4* __restrict__ out4 =
            (float4*)(out + ((size_t)n * C_ + c0) * PER_CH);

#pragma unroll
        for (unsigned it = 0; it < 7; ++it) {
            const unsigned cl = it * 5u + tc;  // local channel
            if (cl >= CPB) continue;           // only trims the last iteration
            const char* pb = (const char*)s_plane + cl * (PER_CH * 4);

            float4 o;
            {
                const float* p0 = (const float*)(pb + O00.x);
                const float* p1 = (const float*)(pb + O10.x);
                float v00 = p0[0], v01 = p0[1];   // -> ds_read2_b32
                float v10 = p1[0], v11 = p1[1];
                o.x = (fmaf(MW.x, v01, v00) + MH.x * fmaf(MW.x, v11, v10)) * INV.x;
            }
            {
                const float* p0 = (const float*)(pb + O00.y);
                const float* p1 = (const float*)(pb + O10.y);
                float v00 = p0[0], v01 = p0[1];
                float v10 = p1[0], v11 = p1[1];
                o.y = (fmaf(MW.y, v01, v00) + MH.y * fmaf(MW.y, v11, v10)) * INV.y;
            }
            {
                const float* p0 = (const float*)(pb + O00.z);
                const float* p1 = (const float*)(pb + O10.z);
                float v00 = p0[0], v01 = p0[1];
                float v10 = p1[0], v11 = p1[1];
                o.z = (fmaf(MW.z, v01, v00) + MH.z * fmaf(MW.z, v11, v10)) * INV.z;
            }
            {
                const float* p0 = (const float*)(pb + O00.w);
                const float* p1 = (const float*)(pb + O10.w);
                float v00 = p0[0], v01 = p0[1];
                float v10 = p1[0], v11 = p1[1];
                o.w = (fmaf(MW.w, v01, v00) + MH.w * fmaf(MW.w, v11, v10)) * INV.w;
            }

            out4[it * ACT + tid] = o;          // qq = it*245+tid, coalesced
        }
    }
}

extern "C" void kernel_launch(void* const* d_in, const int* in_sizes, int n_in,
                              void* d_out, int out_size, void* d_ws, size_t ws_size,
                              hipStream_t stream) {
    const float* tensor = (const float*)d_in[0];   // [8,1024,14,14] f32
    const float* roi    = (const float*)d_in[1];   // [512,5] f32
    float* out = (float*)d_out;                    // [512,1024,14,14] f32

    const int blocks = (out_size / (CPB * PER_CH));  // 512 * 32 = 16,384
    roi_pool_kernel<<<blocks, 256, 0, stream>>>(tensor, roi, out);
}